// Round 1
// baseline (598.176 us; speedup 1.0000x reference)
//
#include <hip/hip_runtime.h>
#include <hip/hip_bf16.h>
#include <math.h>

#define B_  128
#define S_  2048
#define DI  512
#define DC  512

#define BM 128
#define BN 128
#define BK 64

typedef __attribute__((ext_vector_type(8))) __bf16 bf16x8;
typedef __attribute__((ext_vector_type(4))) float  f32x4;
typedef __attribute__((ext_vector_type(4))) unsigned short us4;

__device__ __forceinline__ float fast_tanh(float x) {
    x = fminf(fmaxf(x, -15.f), 15.f);
    float e = __expf(2.f * x);
    return (e - 1.f) / (e + 1.f);
}

__device__ __forceinline__ unsigned short f2bf(float f) {
    unsigned int u = __float_as_uint(f);
    u += 0x7FFF + ((u >> 16) & 1);   // round-to-nearest-even
    return (unsigned short)(u >> 16);
}

// q[b][e] = b_in[e] + b_ctx[e] + sum_d input[b][d] * W_in[d][e]
__global__ __launch_bounds__(256) void qb_kernel(
    const float* __restrict__ input, const float* __restrict__ W_in,
    const float* __restrict__ b_in, const float* __restrict__ b_ctx,
    float* __restrict__ qb)
{
    __shared__ float sIn[DI];
    int b = blockIdx.x, t = threadIdx.x;
    for (int i = t; i < DI; i += 256) sIn[i] = input[b * DI + i];
    __syncthreads();
    int e0 = t * 2;
    float a0 = b_in[e0] + b_ctx[e0];
    float a1 = b_in[e0 + 1] + b_ctx[e0 + 1];
    for (int d = 0; d < DI; ++d) {
        float v = sIn[d];
        const float* w = W_in + (size_t)d * DC + e0;
        a0 += v * w[0];
        a1 += v * w[1];
    }
    qb[b * DC + e0] = a0;
    qb[b * DC + e0 + 1] = a1;
}

// Wt[e][d] = bf16(W_ctx[d][e])
__global__ __launch_bounds__(256) void wt_kernel(
    const float* __restrict__ W_ctx, unsigned short* __restrict__ Wt)
{
    int idx = blockIdx.x * 256 + threadIdx.x;   // over 512*512
    int d = idx >> 9, e = idx & 511;
    Wt[e * 512 + d] = f2bf(W_ctx[idx]);
}

// Fused score GEMM: spart[nblk][row] = sum_{j in nblk's 128 cols} w[j]*tanh(qb[b][j] + (ctx@Wctx)[row][j])
__global__ __launch_bounds__(256) void score_kernel(
    const float* __restrict__ ctx,          // [B*S, DC] fp32
    const unsigned short* __restrict__ Wt,  // [DC(e)][DC(d)] bf16
    const float* __restrict__ qb,           // [B][DC] (q + b_in + b_ctx)
    const float* __restrict__ wsc,          // [DC]
    float* __restrict__ spart)              // [DC/BN][B*S]
{
    __shared__ unsigned short As[BM * BK];  // swizzled
    __shared__ unsigned short Bs[BN * BK];  // swizzled (Wt tile, [col][k])
    __shared__ float sred[2][BM];

    const int t = threadIdx.x;
    const int mblk = blockIdx.x, nblk = blockIdx.y;
    const int row0 = mblk * BM;
    const int col0 = nblk * BN;
    const int bidx = row0 >> 11;            // batch index (2048 rows per batch, BM|2048)

    const int lane = t & 63, wid = t >> 6;
    const int wr = wid >> 1, wc = wid & 1;
    const int lr = lane & 15, half = lane >> 4;

    f32x4 acc[4][4] = {};

    for (int k0 = 0; k0 < DC; k0 += BK) {
        // stage A: ctx fp32 -> bf16 (reg-staged so we can swizzle)
        #pragma unroll
        for (int it = 0; it < 8; ++it) {
            int u = it * 256 + t;
            int r = u >> 4, c = (u & 15) * 4;
            const float4 v = *(const float4*)(ctx + (size_t)(row0 + r) * DC + k0 + c);
            us4 w;
            w.x = f2bf(v.x); w.y = f2bf(v.y); w.z = f2bf(v.z); w.w = f2bf(v.w);
            int off = ((r * BK + c) * 2) ^ ((r & 7) << 4);
            *(us4*)((char*)As + off) = w;
        }
        // stage B: Wt rows (already bf16)
        #pragma unroll
        for (int it = 0; it < 8; ++it) {
            int u = it * 256 + t;
            int j = u >> 4, c = (u & 15) * 4;
            us4 w = *(const us4*)(Wt + (size_t)(col0 + j) * DC + k0 + c);
            int off = ((j * BK + c) * 2) ^ ((j & 7) << 4);
            *(us4*)((char*)Bs + off) = w;
        }
        __syncthreads();
        #pragma unroll
        for (int kk = 0; kk < BK; kk += 32) {
            bf16x8 af[4], bfr[4];
            int cb = (kk + half * 8) * 2;   // byte offset of this lane's k-slice
            #pragma unroll
            for (int fm = 0; fm < 4; ++fm) {
                int r = wr * 64 + fm * 16 + lr;
                int off = (r * (BK * 2) + cb) ^ ((r & 7) << 4);
                af[fm] = *(const bf16x8*)((const char*)As + off);
            }
            #pragma unroll
            for (int fn = 0; fn < 4; ++fn) {
                int j = wc * 64 + fn * 16 + lr;
                int off = (j * (BK * 2) + cb) ^ ((j & 7) << 4);
                bfr[fn] = *(const bf16x8*)((const char*)Bs + off);
            }
            #pragma unroll
            for (int fm = 0; fm < 4; ++fm)
                #pragma unroll
                for (int fn = 0; fn < 4; ++fn)
                    acc[fm][fn] = __builtin_amdgcn_mfma_f32_16x16x32_bf16(
                        af[fm], bfr[fn], acc[fm][fn], 0, 0, 0);
        }
        __syncthreads();
    }

    // epilogue: t = w[j]*tanh(qb[j]+k), reduce over the 128 cols this block owns
    float wv[4], qv[4];
    #pragma unroll
    for (int fn = 0; fn < 4; ++fn) {
        int j = col0 + wc * 64 + fn * 16 + lr;
        wv[fn] = wsc[j];
        qv[fn] = qb[bidx * DC + j];
    }
    #pragma unroll
    for (int fm = 0; fm < 4; ++fm) {
        #pragma unroll
        for (int reg = 0; reg < 4; ++reg) {
            float s = 0.f;
            #pragma unroll
            for (int fn = 0; fn < 4; ++fn)
                s += wv[fn] * fast_tanh(qv[fn] + acc[fm][fn][reg]);
            // reduce across the 16 lanes sharing this output row
            #pragma unroll
            for (int m = 8; m >= 1; m >>= 1)
                s += __shfl_xor(s, m, 64);
            if (lr == 0)
                sred[wc][wr * 64 + fm * 16 + half * 4 + reg] = s;
        }
    }
    __syncthreads();
    if (t < BM)
        spart[(size_t)nblk * (B_ * S_) + row0 + t] = sred[0][t] + sred[1][t];
}

// masked softmax over S per batch row; writes attn (output 1)
__global__ __launch_bounds__(256) void softmax_kernel(
    const float* __restrict__ spart, const int* __restrict__ mask,
    float* __restrict__ attn)
{
    int b = blockIdx.x, t = threadIdx.x;
    __shared__ float red[8];
    const size_t NS = (size_t)B_ * S_;
    float v[8];
    float mx = -1e30f;
    #pragma unroll
    for (int i = 0; i < 8; ++i) {
        size_t idx = (size_t)b * S_ + t + i * 256;
        float sc = spart[idx] + spart[NS + idx] + spart[2 * NS + idx] + spart[3 * NS + idx];
        if (mask[idx] != 0) sc = -1e30f;
        v[i] = sc;
        mx = fmaxf(mx, sc);
    }
    #pragma unroll
    for (int m = 32; m >= 1; m >>= 1) mx = fmaxf(mx, __shfl_xor(mx, m, 64));
    if ((t & 63) == 0) red[t >> 6] = mx;
    __syncthreads();
    float bm = fmaxf(fmaxf(red[0], red[1]), fmaxf(red[2], red[3]));
    float sum = 0.f;
    #pragma unroll
    for (int i = 0; i < 8; ++i) { v[i] = __expf(v[i] - bm); sum += v[i]; }
    #pragma unroll
    for (int m = 32; m >= 1; m >>= 1) sum += __shfl_xor(sum, m, 64);
    __syncthreads();
    if ((t & 63) == 0) red[t >> 6] = sum;
    __syncthreads();
    float inv = 1.f / (red[0] + red[1] + red[2] + red[3]);
    #pragma unroll
    for (int i = 0; i < 8; ++i)
        attn[(size_t)b * S_ + t + i * 256] = v[i] * inv;
}

// ctxv[b][d] += sum_s attn[b][s]*ctx[b][s][d]  (16 s-chunks per b, atomics)
__global__ __launch_bounds__(256) void ctxv_kernel(
    const float* __restrict__ ctx, const float* __restrict__ attn,
    float* __restrict__ ctxv)
{
    int b = blockIdx.x >> 4;
    int s0 = (blockIdx.x & 15) * 128;
    int t = threadIdx.x;
    __shared__ float sA[128];
    if (t < 128) sA[t] = attn[(size_t)b * S_ + s0 + t];
    __syncthreads();
    int d0 = t * 2;
    float a0 = 0.f, a1 = 0.f;
    for (int s = 0; s < 128; ++s) {
        float w = sA[s];
        const float2 c = *(const float2*)(ctx + (size_t)(b * S_ + s0 + s) * DC + d0);
        a0 += w * c.x;
        a1 += w * c.y;
    }
    atomicAdd(&ctxv[b * DC + d0], a0);
    atomicAdd(&ctxv[b * DC + d0 + 1], a1);
}

// x[b][i] = tanh(cat(ctxv,input) @ W_out + b_out)
__global__ __launch_bounds__(256) void out_kernel(
    const float* __restrict__ ctxv, const float* __restrict__ input,
    const float* __restrict__ W_out, const float* __restrict__ b_out,
    float* __restrict__ x)
{
    __shared__ float sc[DC + DI];
    int b = blockIdx.x, t = threadIdx.x;
    for (int i = t; i < DC; i += 256) sc[i] = ctxv[b * DC + i];
    for (int i = t; i < DI; i += 256) sc[DC + i] = input[b * DI + i];
    __syncthreads();
    int e0 = t * 2;
    float a0 = b_out[e0], a1 = b_out[e0 + 1];
    for (int d = 0; d < DC + DI; ++d) {
        float v = sc[d];
        const float* w = W_out + (size_t)d * DI + e0;
        a0 += v * w[0];
        a1 += v * w[1];
    }
    x[b * DI + e0] = fast_tanh(a0);
    x[b * DI + e0 + 1] = fast_tanh(a1);
}

extern "C" void kernel_launch(void* const* d_in, const int* in_sizes, int n_in,
                              void* d_out, int out_size, void* d_ws, size_t ws_size,
                              hipStream_t stream) {
    const float* input = (const float*)d_in[0];
    const float* ctx   = (const float*)d_in[1];
    const int*   mask  = (const int*)d_in[2];
    const float* W_in  = (const float*)d_in[3];
    const float* b_in  = (const float*)d_in[4];
    const float* W_ctx = (const float*)d_in[5];
    const float* b_ctx = (const float*)d_in[6];
    const float* wsc   = (const float*)d_in[7];
    const float* W_out = (const float*)d_in[8];
    const float* b_out = (const float*)d_in[9];

    float* x_out = (float*)d_out;               // [B, DI]
    float* attn  = (float*)d_out + B_ * DI;     // [B, S]

    char* ws = (char*)d_ws;
    float* qb = (float*)ws;                    ws += (size_t)B_ * DC * 4;
    unsigned short* Wt = (unsigned short*)ws;  ws += (size_t)DC * DC * 2;
    float* spart = (float*)ws;                 ws += 4 * (size_t)B_ * S_ * 4;
    float* ctxv = (float*)ws;                  ws += (size_t)B_ * DC * 4;

    hipMemsetAsync(ctxv, 0, (size_t)B_ * DC * 4, stream);

    qb_kernel<<<B_, 256, 0, stream>>>(input, W_in, b_in, b_ctx, qb);
    wt_kernel<<<DC * DC / 256, 256, 0, stream>>>(W_ctx, Wt);
    score_kernel<<<dim3((B_ * S_) / BM, DC / BN), 256, 0, stream>>>(ctx, Wt, qb, wsc, spart);
    softmax_kernel<<<B_, 256, 0, stream>>>(spart, mask, attn);
    ctxv_kernel<<<B_ * 16, 256, 0, stream>>>(ctx, attn, ctxv);
    out_kernel<<<B_, 256, 0, stream>>>(ctxv, input, W_out, b_out, x_out);
}

// Round 2
// 440.323 us; speedup vs baseline: 1.3585x; 1.3585x over previous
//
#include <hip/hip_runtime.h>
#include <hip/hip_bf16.h>
#include <math.h>

#define B_  128
#define S_  2048
#define DI  512
#define DC  512

typedef __attribute__((ext_vector_type(8))) __bf16 bf16x8;
typedef __attribute__((ext_vector_type(4))) float  f32x4;
typedef __attribute__((ext_vector_type(4))) unsigned short us4;
typedef __attribute__((ext_vector_type(8))) unsigned short us8;

__device__ __forceinline__ float fast_tanh(float x) {
    x = fminf(fmaxf(x, -15.f), 15.f);
    float e = __expf(2.f * x);
    return (e - 1.f) / (e + 1.f);
}

__device__ __forceinline__ unsigned short f2bf(float f) {
    unsigned int u = __float_as_uint(f);
    u += 0x7FFF + ((u >> 16) & 1);   // RNE
    return (unsigned short)(u >> 16);
}

__device__ __forceinline__ float bf2f(unsigned int lo16) {
    return __uint_as_float(lo16 << 16);
}

// q[b][e] = b_in[e] + b_ctx[e] + sum_d input[b][d] * W_in[d][e]
__global__ __launch_bounds__(256) void qb_kernel(
    const float* __restrict__ input, const float* __restrict__ W_in,
    const float* __restrict__ b_in, const float* __restrict__ b_ctx,
    float* __restrict__ qb)
{
    __shared__ float sIn[DI];
    int b = blockIdx.x, t = threadIdx.x;
    for (int i = t; i < DI; i += 256) sIn[i] = input[b * DI + i];
    __syncthreads();
    int e0 = t * 2;
    float a0 = b_in[e0] + b_ctx[e0];
    float a1 = b_in[e0 + 1] + b_ctx[e0 + 1];
    for (int d = 0; d < DI; ++d) {
        float v = sIn[d];
        const float* w = W_in + (size_t)d * DC + e0;
        a0 += v * w[0];
        a1 += v * w[1];
    }
    qb[b * DC + e0] = a0;
    qb[b * DC + e0 + 1] = a1;
}

// Wt[e][d] = bf16(W_ctx[d][e])
__global__ __launch_bounds__(256) void wt_kernel(
    const float* __restrict__ W_ctx, unsigned short* __restrict__ Wt)
{
    int idx = blockIdx.x * 256 + threadIdx.x;   // over 512*512
    int d = idx >> 9, e = idx & 511;
    Wt[e * 512 + d] = f2bf(W_ctx[idx]);
}

// Fused: scores + block-local softmax partials + partial context sums.
// One block = 64 ctx rows ((b,s) pairs). ctx read from HBM exactly once.
__global__ __launch_bounds__(256, 2) void score_kernel(
    const float* __restrict__ ctx,          // [B*S, DC] fp32
    const unsigned short* __restrict__ Wt,  // [e][d] bf16
    const float* __restrict__ qb,           // [B][DC]
    const float* __restrict__ wsc,          // [DC]
    const int* __restrict__ mask,           // [B*S]
    float* __restrict__ scores_ws,          // [B*S] raw masked scores
    float* __restrict__ pv_ws,              // [nblocks][512]
    float* __restrict__ ml_ws)              // [nblocks][2] (m, l)
{
    __shared__ __align__(16) unsigned short ctxs[64 * 512];  // 64 KB, swizzled
    __shared__ __align__(16) unsigned short Bs[256 * 32];    // 16 KB, swizzled

    const int t = threadIdx.x;
    const int row0 = blockIdx.x * 64;       // global (b,s) row base
    const int bidx = row0 >> 11;            // batch index
    const int lane = t & 63;
    const int wc = t >> 6;                  // wave id = column quarter
    const int lr = lane & 15, half = lane >> 4;

    // prefetch Bs tile for step 0 (overlaps ctx staging)
    us8 bcur[4], bnxt[4];
    {
        const unsigned short* src = Wt + (size_t)t * DC;   // nblk=0, k0=0
        #pragma unroll
        for (int i = 0; i < 4; ++i) bcur[i] = *(const us8*)(src + i * 8);
    }

    // stage ctx rows -> bf16 LDS (the only HBM read of ctx in this kernel)
    #pragma unroll 8
    for (int i = 0; i < 16; ++i) {
        int u = i * 256 + t;
        int r = u >> 6, kg = u & 63;
        const float4* src = (const float4*)(ctx + (size_t)(row0 + r) * DC + kg * 8);
        float4 va = src[0], vb = src[1];
        us8 w;
        w[0] = f2bf(va.x); w[1] = f2bf(va.y); w[2] = f2bf(va.z); w[3] = f2bf(va.w);
        w[4] = f2bf(vb.x); w[5] = f2bf(vb.y); w[6] = f2bf(vb.z); w[7] = f2bf(vb.w);
        *(us8*)((char*)ctxs + ((r * 1024 + kg * 16) ^ ((r & 7) << 4))) = w;
    }
    __syncthreads();

    f32x4 acc[4][4] = {};
    float srow[4][4] = {};

    for (int step = 0; step < 32; ++step) {
        const int k0 = (step & 15) * 32;
        // write current B tile (cols [nblk*256, +256), k [k0, k0+32))
        #pragma unroll
        for (int i = 0; i < 4; ++i)
            *(us8*)((char*)Bs + ((t * 64 + i * 16) ^ ((t & 7) << 4))) = bcur[i];
        __syncthreads();                 // vmcnt already drained (bcur consumed)
        // prefetch next B tile; stays in flight across the raw barrier below
        if (step < 31) {
            int sn = step + 1;
            const unsigned short* src =
                Wt + (size_t)((sn >> 4) * 256 + t) * DC + (sn & 15) * 32;
            #pragma unroll
            for (int i = 0; i < 4; ++i) bnxt[i] = *(const us8*)(src + i * 8);
        }
        bf16x8 af[4], bfr[4];
        #pragma unroll
        for (int fm = 0; fm < 4; ++fm) {
            int r = fm * 16 + lr;
            int off = (r * 1024 + k0 * 2 + half * 16) ^ ((r & 7) << 4);
            af[fm] = *(const bf16x8*)((const char*)ctxs + off);
        }
        #pragma unroll
        for (int fn = 0; fn < 4; ++fn) {
            int j = wc * 64 + fn * 16 + lr;
            int off = (j * 64 + half * 16) ^ ((j & 7) << 4);
            bfr[fn] = *(const bf16x8*)((const char*)Bs + off);
        }
        #pragma unroll
        for (int fm = 0; fm < 4; ++fm)
            #pragma unroll
            for (int fn = 0; fn < 4; ++fn)
                acc[fm][fn] = __builtin_amdgcn_mfma_f32_16x16x32_bf16(
                    af[fm], bfr[fn], acc[fm][fn], 0, 0, 0);

        if ((step & 15) == 15) {        // end of this 256-col half: fold tanh
            const int nb2 = step >> 4;
            #pragma unroll
            for (int fn = 0; fn < 4; ++fn) {
                int j = nb2 * 256 + wc * 64 + fn * 16 + lr;
                float wvv = wsc[j];
                float qvv = qb[bidx * DC + j];
                #pragma unroll
                for (int fm = 0; fm < 4; ++fm)
                    #pragma unroll
                    for (int reg = 0; reg < 4; ++reg)
                        srow[fm][reg] += wvv * fast_tanh(qvv + acc[fm][fn][reg]);
            }
            #pragma unroll
            for (int fm = 0; fm < 4; ++fm)
                #pragma unroll
                for (int fn = 0; fn < 4; ++fn)
                    acc[fm][fn] = (f32x4){0.f, 0.f, 0.f, 0.f};
        }

        asm volatile("s_waitcnt lgkmcnt(0)" ::: "memory");
        __builtin_amdgcn_s_barrier();    // raw: prefetch loads stay in flight
        asm volatile("" ::: "memory");
        #pragma unroll
        for (int i = 0; i < 4; ++i) bcur[i] = bnxt[i];
    }

    // ---- tail: block softmax partials + pv, all from LDS ----
    float* f = (float*)Bs;               // sred[4][64] | p[64] | spare
    #pragma unroll
    for (int fm = 0; fm < 4; ++fm)
        #pragma unroll
        for (int reg = 0; reg < 4; ++reg) {
            float s = srow[fm][reg];
            #pragma unroll
            for (int m = 8; m >= 1; m >>= 1) s += __shfl_xor(s, m, 64);
            if (lr == 0) f[wc * 64 + fm * 16 + half * 4 + reg] = s;
        }
    __syncthreads();

    if (t < 64) {                        // whole wave 0
        float sc = f[t] + f[64 + t] + f[128 + t] + f[192 + t];
        if (mask[row0 + t] != 0) sc = -1e30f;
        scores_ws[row0 + t] = sc;
        float mx = sc;
        #pragma unroll
        for (int m = 32; m >= 1; m >>= 1) mx = fmaxf(mx, __shfl_xor(mx, m, 64));
        float pe = __expf(sc - mx);
        f[256 + t] = pe;
        float ls = pe;
        #pragma unroll
        for (int m = 32; m >= 1; m >>= 1) ls += __shfl_xor(ls, m, 64);
        if (t == 0) {
            ml_ws[blockIdx.x * 2]     = mx;
            ml_ws[blockIdx.x * 2 + 1] = ls;
        }
    }
    __syncthreads();

    const float* pp = f + 256;
    int d0 = t * 2;
    float a0 = 0.f, a1 = 0.f;
    #pragma unroll 8
    for (int s = 0; s < 64; ++s) {
        float w = pp[s];
        unsigned int u = *(const unsigned int*)
            ((const char*)ctxs + (s * 1024 + ((d0 * 2) ^ ((s & 7) << 4))));
        a0 += w * bf2f(u & 0xffffu);
        a1 += w * bf2f(u >> 16);
    }
    pv_ws[(size_t)blockIdx.x * 512 + d0]     = a0;
    pv_ws[(size_t)blockIdx.x * 512 + d0 + 1] = a1;
}

// Exact cross-block softmax merge: attn + ctxv
__global__ __launch_bounds__(256) void combine_kernel(
    const float* __restrict__ pv, const float* __restrict__ ml,
    const float* __restrict__ scores,
    float* __restrict__ ctxv, float* __restrict__ attn)
{
    int b = blockIdx.x, t = threadIdx.x;
    __shared__ float sm[32], sl[32], sw[32];
    if (t < 32) {
        sm[t] = ml[(b * 32 + t) * 2];
        sl[t] = ml[(b * 32 + t) * 2 + 1];
    }
    __syncthreads();
    float mstar = -1e30f;
    #pragma unroll
    for (int i = 0; i < 32; ++i) mstar = fmaxf(mstar, sm[i]);
    if (t < 32) sw[t] = __expf(sm[t] - mstar);
    __syncthreads();
    float L = 0.f;
    #pragma unroll
    for (int i = 0; i < 32; ++i) L += sw[i] * sl[i];
    float invL = 1.f / L;

    int d0 = t * 2;
    float c0 = 0.f, c1 = 0.f;
    #pragma unroll
    for (int i = 0; i < 32; ++i) {
        float w = sw[i];
        const float2 v = *(const float2*)(pv + (size_t)(b * 32 + i) * 512 + d0);
        c0 += w * v.x; c1 += w * v.y;
    }
    ctxv[b * DC + d0]     = c0 * invL;
    ctxv[b * DC + d0 + 1] = c1 * invL;

    for (int s = t; s < S_; s += 256)
        attn[(size_t)b * S_ + s] = __expf(scores[(size_t)b * S_ + s] - mstar) * invL;
}

// x[b][i] = tanh(cat(ctxv,input) @ W_out + b_out)
__global__ __launch_bounds__(256) void out_kernel(
    const float* __restrict__ ctxv, const float* __restrict__ input,
    const float* __restrict__ W_out, const float* __restrict__ b_out,
    float* __restrict__ x)
{
    __shared__ float sc[DC + DI];
    int b = blockIdx.x, t = threadIdx.x;
    for (int i = t; i < DC; i += 256) sc[i] = ctxv[b * DC + i];
    for (int i = t; i < DI; i += 256) sc[DC + i] = input[b * DI + i];
    __syncthreads();
    int e0 = t * 2;
    float a0 = b_out[e0], a1 = b_out[e0 + 1];
    for (int d = 0; d < DC + DI; ++d) {
        float v = sc[d];
        const float* w = W_out + (size_t)d * DI + e0;
        a0 += v * w[0];
        a1 += v * w[1];
    }
    x[b * DI + e0] = fast_tanh(a0);
    x[b * DI + e0 + 1] = fast_tanh(a1);
}

extern "C" void kernel_launch(void* const* d_in, const int* in_sizes, int n_in,
                              void* d_out, int out_size, void* d_ws, size_t ws_size,
                              hipStream_t stream) {
    const float* input = (const float*)d_in[0];
    const float* ctx   = (const float*)d_in[1];
    const int*   mask  = (const int*)d_in[2];
    const float* W_in  = (const float*)d_in[3];
    const float* b_in  = (const float*)d_in[4];
    const float* W_ctx = (const float*)d_in[5];
    const float* b_ctx = (const float*)d_in[6];
    const float* wsc   = (const float*)d_in[7];
    const float* W_out = (const float*)d_in[8];
    const float* b_out = (const float*)d_in[9];

    float* x_out = (float*)d_out;               // [B, DI]
    float* attn  = (float*)d_out + B_ * DI;     // [B, S]

    const int NBLK = (B_ * S_) / 64;            // 4096 score blocks

    char* ws = (char*)d_ws;
    float* qb = (float*)ws;                    ws += (size_t)B_ * DC * 4;
    unsigned short* Wt = (unsigned short*)ws;  ws += (size_t)DC * DC * 2;
    float* scores_ws = (float*)ws;             ws += (size_t)B_ * S_ * 4;
    float* pv_ws = (float*)ws;                 ws += (size_t)NBLK * 512 * 4;
    float* ml_ws = (float*)ws;                 ws += (size_t)NBLK * 2 * 4;
    float* ctxv = (float*)ws;                  ws += (size_t)B_ * DC * 4;

    qb_kernel<<<B_, 256, 0, stream>>>(input, W_in, b_in, b_ctx, qb);
    wt_kernel<<<DC * DC / 256, 256, 0, stream>>>(W_ctx, Wt);
    score_kernel<<<NBLK, 256, 0, stream>>>(ctx, Wt, qb, wsc, mask,
                                           scores_ws, pv_ws, ml_ws);
    combine_kernel<<<B_, 256, 0, stream>>>(pv_ws, ml_ws, scores_ws, ctxv, attn);
    out_kernel<<<B_, 256, 0, stream>>>(ctxv, input, W_out, b_out, x_out);
}

// Round 3
// 317.755 us; speedup vs baseline: 1.8825x; 1.3857x over previous
//
#include <hip/hip_runtime.h>
#include <hip/hip_bf16.h>
#include <math.h>

#define B_  128
#define S_  2048
#define DI  512
#define DC  512

typedef __attribute__((ext_vector_type(8))) __bf16 bf16x8;
typedef __attribute__((ext_vector_type(4))) float  f32x4;
typedef __attribute__((ext_vector_type(8))) unsigned short us8;

__device__ __forceinline__ float fast_tanh(float x) {
    // tanh(x) = 1 - 2/(exp(2x)+1); inf-safe at both ends
    float e = __expf(2.f * x);
    return 1.f - 2.f * __builtin_amdgcn_rcpf(e + 1.f);
}

__device__ __forceinline__ unsigned short f2bf(float f) {
    unsigned int u = __float_as_uint(f);
    u += 0x7FFF + ((u >> 16) & 1);   // RNE
    return (unsigned short)(u >> 16);
}

__device__ __forceinline__ float bf2f(unsigned int lo16) {
    return __uint_as_float(lo16 << 16);
}

// q[b][e] = b_in[e] + b_ctx[e] + sum_d input[b][d] * W_in[d][e]
__global__ __launch_bounds__(256) void qb_kernel(
    const float* __restrict__ input, const float* __restrict__ W_in,
    const float* __restrict__ b_in, const float* __restrict__ b_ctx,
    float* __restrict__ qb)
{
    __shared__ float sIn[DI];
    int b = blockIdx.x, t = threadIdx.x;
    for (int i = t; i < DI; i += 256) sIn[i] = input[b * DI + i];
    __syncthreads();
    int e0 = t * 2;
    float a0 = b_in[e0] + b_ctx[e0];
    float a1 = b_in[e0 + 1] + b_ctx[e0 + 1];
    for (int d = 0; d < DI; ++d) {
        float v = sIn[d];
        const float* w = W_in + (size_t)d * DC + e0;
        a0 += v * w[0];
        a1 += v * w[1];
    }
    qb[b * DC + e0] = a0;
    qb[b * DC + e0 + 1] = a1;
}

// Repack W_ctx into MFMA B-fragment order:
// WtF[s][g][lane][j] = bf16(W_ctx[s*32 + (lane>>4)*8 + j][g*16 + (lane&15)])
// so each (s,g) is one fully-coalesced 1KB wave load = one bfr fragment.
__global__ __launch_bounds__(256) void wt_kernel(
    const float* __restrict__ W_ctx, unsigned short* __restrict__ WtF)
{
    int tid = blockIdx.x * 256 + threadIdx.x;   // [0, 16*32*64)
    int s   = tid >> 11;
    int rem = tid & 2047;
    int g   = rem >> 6;
    int l   = rem & 63;
    int c   = g * 16 + (l & 15);
    int k0  = s * 32 + (l >> 4) * 8;
    us8 w;
    #pragma unroll
    for (int j = 0; j < 8; ++j)
        w[j] = f2bf(W_ctx[(size_t)(k0 + j) * DC + c]);
    *(us8*)(WtF + (size_t)tid * 8) = w;
}

// Fused: scores + block-local softmax partials + partial context sums.
// One block = 64 ctx rows. ctx read from HBM exactly once; B-fragments
// loaded directly from L2-resident WtF (coalesced). NO barriers in K-loop.
__global__ __launch_bounds__(256, 2) void score_kernel(
    const float* __restrict__ ctx,          // [B*S, DC] fp32
    const unsigned short* __restrict__ WtF, // fragment-ordered bf16
    const float* __restrict__ qb,           // [B][DC]
    const float* __restrict__ wsc,          // [DC]
    const int* __restrict__ mask,           // [B*S]
    float* __restrict__ scores_ws,          // [B*S]
    float* __restrict__ pv_ws,              // [nblocks][512]
    float* __restrict__ ml_ws)              // [nblocks][2]
{
    __shared__ __align__(16) unsigned short ctxs[64 * 512];  // 64 KB swizzled
    __shared__ float sred[4][64];
    __shared__ float sp[64];

    const int t = threadIdx.x;
    const int row0 = blockIdx.x * 64;
    const int bidx = row0 >> 11;
    const int lane = t & 63;
    const int wc = t >> 6;                  // wave id -> cols [wc*128, +128)
    const int lr = lane & 15, half = lane >> 4;   // half in 0..3

    // ---- stage ctx -> bf16 LDS (only HBM read of ctx) ----
    #pragma unroll
    for (int i = 0; i < 16; ++i) {
        int u = i * 256 + t;
        int r = u >> 6, kg = u & 63;
        const float4* src = (const float4*)(ctx + (size_t)(row0 + r) * DC + kg * 8);
        float4 va = src[0], vb = src[1];
        us8 w;
        w[0] = f2bf(va.x); w[1] = f2bf(va.y); w[2] = f2bf(va.z); w[3] = f2bf(va.w);
        w[4] = f2bf(vb.x); w[5] = f2bf(vb.y); w[6] = f2bf(vb.z); w[7] = f2bf(vb.w);
        *(us8*)((char*)ctxs + ((r * 1024 + kg * 16) ^ ((r & 7) << 4))) = w;
    }
    __syncthreads();

    // ---- K-loop: free-running, no barriers ----
    f32x4 acc[4][8] = {};
    #pragma unroll 2
    for (int s = 0; s < 16; ++s) {
        bf16x8 bfr[8];
        const us8* wsrc = (const us8*)(WtF + ((size_t)(s * 32 + wc * 8) * 64 + lane) * 8);
        #pragma unroll
        for (int fn = 0; fn < 8; ++fn)
            bfr[fn] = *(const bf16x8*)(wsrc + fn * 64);
        bf16x8 af[4];
        #pragma unroll
        for (int fm = 0; fm < 4; ++fm) {
            int r = fm * 16 + lr;
            af[fm] = *(const bf16x8*)((const char*)ctxs +
                        ((r * 1024 + s * 64 + half * 16) ^ ((r & 7) << 4)));
        }
        #pragma unroll
        for (int fm = 0; fm < 4; ++fm)
            #pragma unroll
            for (int fn = 0; fn < 8; ++fn)
                acc[fm][fn] = __builtin_amdgcn_mfma_f32_16x16x32_bf16(
                    af[fm], bfr[fn], acc[fm][fn], 0, 0, 0);
    }

    // ---- epilogue: fold tanh, reduce rows ----
    float wv[8], qv[8];
    #pragma unroll
    for (int fn = 0; fn < 8; ++fn) {
        int j = wc * 128 + fn * 16 + lr;
        wv[fn] = wsc[j];
        qv[fn] = qb[bidx * DC + j];
    }
    #pragma unroll
    for (int fm = 0; fm < 4; ++fm) {
        #pragma unroll
        for (int reg = 0; reg < 4; ++reg) {
            float ssum = 0.f;
            #pragma unroll
            for (int fn = 0; fn < 8; ++fn)
                ssum += wv[fn] * fast_tanh(qv[fn] + acc[fm][fn][reg]);
            #pragma unroll
            for (int m = 8; m >= 1; m >>= 1)
                ssum += __shfl_xor(ssum, m, 64);
            if (lr == 0)
                sred[wc][fm * 16 + half * 4 + reg] = ssum;
        }
    }
    __syncthreads();

    if (t < 64) {                        // wave 0: block softmax partials
        float sc = sred[0][t] + sred[1][t] + sred[2][t] + sred[3][t];
        if (mask[row0 + t] != 0) sc = -1e30f;
        scores_ws[row0 + t] = sc;
        float mx = sc;
        #pragma unroll
        for (int m = 32; m >= 1; m >>= 1) mx = fmaxf(mx, __shfl_xor(mx, m, 64));
        float pe = __expf(sc - mx);
        sp[t] = pe;
        float ls = pe;
        #pragma unroll
        for (int m = 32; m >= 1; m >>= 1) ls += __shfl_xor(ls, m, 64);
        if (t == 0) {
            ml_ws[blockIdx.x * 2]     = mx;
            ml_ws[blockIdx.x * 2 + 1] = ls;
        }
    }
    __syncthreads();

    // ---- pv partial: all from LDS ----
    int d0 = t * 2;
    float a0 = 0.f, a1 = 0.f;
    #pragma unroll 8
    for (int s = 0; s < 64; ++s) {
        float w = sp[s];
        unsigned int u = *(const unsigned int*)
            ((const char*)ctxs + ((s * 1024 + d0 * 2) ^ ((s & 7) << 4)));
        a0 += w * bf2f(u & 0xffffu);
        a1 += w * bf2f(u >> 16);
    }
    pv_ws[(size_t)blockIdx.x * 512 + d0]     = a0;
    pv_ws[(size_t)blockIdx.x * 512 + d0 + 1] = a1;
}

// Exact cross-block softmax merge: attn + ctxv
__global__ __launch_bounds__(256) void combine_kernel(
    const float* __restrict__ pv, const float* __restrict__ ml,
    const float* __restrict__ scores,
    float* __restrict__ ctxv, float* __restrict__ attn)
{
    int b = blockIdx.x, t = threadIdx.x;
    __shared__ float sm[32], sl[32], sw[32];
    if (t < 32) {
        sm[t] = ml[(b * 32 + t) * 2];
        sl[t] = ml[(b * 32 + t) * 2 + 1];
    }
    __syncthreads();
    float mstar = -1e30f;
    #pragma unroll
    for (int i = 0; i < 32; ++i) mstar = fmaxf(mstar, sm[i]);
    if (t < 32) sw[t] = __expf(sm[t] - mstar);
    __syncthreads();
    float L = 0.f;
    #pragma unroll
    for (int i = 0; i < 32; ++i) L += sw[i] * sl[i];
    float invL = 1.f / L;

    int d0 = t * 2;
    float c0 = 0.f, c1 = 0.f;
    #pragma unroll
    for (int i = 0; i < 32; ++i) {
        float w = sw[i];
        const float2 v = *(const float2*)(pv + (size_t)(b * 32 + i) * 512 + d0);
        c0 += w * v.x; c1 += w * v.y;
    }
    ctxv[b * DC + d0]     = c0 * invL;
    ctxv[b * DC + d0 + 1] = c1 * invL;

    for (int s = t; s < S_; s += 256)
        attn[(size_t)b * S_ + s] = __expf(scores[(size_t)b * S_ + s] - mstar) * invL;
}

// x[b][i] = tanh(cat(ctxv,input) @ W_out + b_out)
__global__ __launch_bounds__(256) void out_kernel(
    const float* __restrict__ ctxv, const float* __restrict__ input,
    const float* __restrict__ W_out, const float* __restrict__ b_out,
    float* __restrict__ x)
{
    __shared__ float sc[DC + DI];
    int b = blockIdx.x, t = threadIdx.x;
    for (int i = t; i < DC; i += 256) sc[i] = ctxv[b * DC + i];
    for (int i = t; i < DI; i += 256) sc[DC + i] = input[b * DI + i];
    __syncthreads();
    int e0 = t * 2;
    float a0 = b_out[e0], a1 = b_out[e0 + 1];
    for (int d = 0; d < DC + DI; ++d) {
        float v = sc[d];
        const float* w = W_out + (size_t)d * DI + e0;
        a0 += v * w[0];
        a1 += v * w[1];
    }
    x[b * DI + e0] = fast_tanh(a0);
    x[b * DI + e0 + 1] = fast_tanh(a1);
}

extern "C" void kernel_launch(void* const* d_in, const int* in_sizes, int n_in,
                              void* d_out, int out_size, void* d_ws, size_t ws_size,
                              hipStream_t stream) {
    const float* input = (const float*)d_in[0];
    const float* ctx   = (const float*)d_in[1];
    const int*   mask  = (const int*)d_in[2];
    const float* W_in  = (const float*)d_in[3];
    const float* b_in  = (const float*)d_in[4];
    const float* W_ctx = (const float*)d_in[5];
    const float* b_ctx = (const float*)d_in[6];
    const float* wsc   = (const float*)d_in[7];
    const float* W_out = (const float*)d_in[8];
    const float* b_out = (const float*)d_in[9];

    float* x_out = (float*)d_out;               // [B, DI]
    float* attn  = (float*)d_out + B_ * DI;     // [B, S]

    const int NBLK = (B_ * S_) / 64;            // 4096 score blocks

    char* ws = (char*)d_ws;
    float* qb = (float*)ws;                    ws += (size_t)B_ * DC * 4;
    unsigned short* WtF = (unsigned short*)ws; ws += (size_t)DC * DC * 2;
    float* scores_ws = (float*)ws;             ws += (size_t)B_ * S_ * 4;
    float* pv_ws = (float*)ws;                 ws += (size_t)NBLK * 512 * 4;
    float* ml_ws = (float*)ws;                 ws += (size_t)NBLK * 2 * 4;
    float* ctxv = (float*)ws;                  ws += (size_t)B_ * DC * 4;

    qb_kernel<<<B_, 256, 0, stream>>>(input, W_in, b_in, b_ctx, qb);
    wt_kernel<<<(16 * 32 * 64) / 256, 256, 0, stream>>>(W_ctx, WtF);
    score_kernel<<<NBLK, 256, 0, stream>>>(ctx, WtF, qb, wsc, mask,
                                           scores_ws, pv_ws, ml_ws);
    combine_kernel<<<B_, 256, 0, stream>>>(pv_ws, ml_ws, scores_ws, ctxv, attn);
    out_kernel<<<B_, 256, 0, stream>>>(ctxv, input, W_out, b_out, x_out);
}

// Round 4
// 284.853 us; speedup vs baseline: 2.0999x; 1.1155x over previous
//
#include <hip/hip_runtime.h>
#include <hip/hip_bf16.h>
#include <math.h>

#define B_  128
#define S_  2048
#define DI  512
#define DC  512

typedef __attribute__((ext_vector_type(8))) __bf16 bf16x8;
typedef __attribute__((ext_vector_type(4))) float  f32x4;
typedef __attribute__((ext_vector_type(8))) unsigned short us8;

__device__ __forceinline__ float fast_tanh(float x) {
    // tanh(x) = 1 - 2/(exp(2x)+1); inf-safe at both ends
    float e = __expf(2.f * x);
    return 1.f - 2.f * __builtin_amdgcn_rcpf(e + 1.f);
}

__device__ __forceinline__ unsigned short f2bf(float f) {
    unsigned int u = __float_as_uint(f);
    u += 0x7FFF + ((u >> 16) & 1);   // RNE
    return (unsigned short)(u >> 16);
}

__device__ __forceinline__ unsigned int pk2(float a, float b) {
    // packed f32x2 -> bf16x2 (v_cvt_pk_bf16_f32), low = a
    union { __hip_bfloat162 h; unsigned int u; } c;
    c.h = __float22bfloat162_rn(make_float2(a, b));
    return c.u;
}

__device__ __forceinline__ float bf2f(unsigned int lo16) {
    return __uint_as_float(lo16 << 16);
}

// q[b][e] = b_in[e] + b_ctx[e] + sum_d input[b][d] * W_in[d][e]
__global__ __launch_bounds__(256) void qb_kernel(
    const float* __restrict__ input, const float* __restrict__ W_in,
    const float* __restrict__ b_in, const float* __restrict__ b_ctx,
    float* __restrict__ qb)
{
    __shared__ float sIn[DI];
    int b = blockIdx.x, t = threadIdx.x;
    for (int i = t; i < DI; i += 256) sIn[i] = input[b * DI + i];
    __syncthreads();
    int e0 = t * 2;
    float a0 = b_in[e0] + b_ctx[e0];
    float a1 = b_in[e0 + 1] + b_ctx[e0 + 1];
    for (int d = 0; d < DI; ++d) {
        float v = sIn[d];
        const float* w = W_in + (size_t)d * DC + e0;
        a0 += v * w[0];
        a1 += v * w[1];
    }
    qb[b * DC + e0] = a0;
    qb[b * DC + e0 + 1] = a1;
}

// Repack W_ctx into MFMA B-fragment order:
// WtF[s][g][lane][j] = bf16(W_ctx[s*32 + (lane>>4)*8 + j][g*16 + (lane&15)])
__global__ __launch_bounds__(256) void wt_kernel(
    const float* __restrict__ W_ctx, unsigned short* __restrict__ WtF)
{
    int tid = blockIdx.x * 256 + threadIdx.x;   // [0, 16*32*64)
    int s   = tid >> 11;
    int rem = tid & 2047;
    int g   = rem >> 6;
    int l   = rem & 63;
    int c   = g * 16 + (l & 15);
    int k0  = s * 32 + (l >> 4) * 8;
    us8 w;
    #pragma unroll
    for (int j = 0; j < 8; ++j)
        w[j] = f2bf(W_ctx[(size_t)(k0 + j) * DC + c]);
    *(us8*)(WtF + (size_t)tid * 8) = w;
}

// Fused: scores + block-local softmax partials + partial context sums.
// 8 waves, 64 ctx rows/block; wave w owns cols [w*64, w*64+64).
// ctx read from HBM exactly once; B-fragments straight from L2; no K-loop barriers.
__global__ __launch_bounds__(512, 4) void score_kernel(
    const float* __restrict__ ctx,          // [B*S, DC] fp32
    const unsigned short* __restrict__ WtF, // fragment-ordered bf16
    const float* __restrict__ qb,           // [B][DC]
    const float* __restrict__ wsc,          // [DC]
    const int* __restrict__ mask,           // [B*S]
    float* __restrict__ scores_ws,          // [B*S]
    float* __restrict__ pv_ws,              // [nblocks][512]
    float* __restrict__ ml_ws)              // [nblocks][2]
{
    __shared__ __align__(16) unsigned short ctxs[64 * 512];  // 64 KB swizzled
    __shared__ float sred[8][64];
    __shared__ float sp[64];

    const int t = threadIdx.x;
    const int row0 = blockIdx.x * 64;
    const int bidx = row0 >> 11;
    const int lane = t & 63;
    const int w = t >> 6;                   // wave id 0..7
    const int lr = lane & 15, half = lane >> 4;

    // ---- stage ctx -> bf16 LDS (only HBM read of ctx) ----
    #pragma unroll
    for (int i = 0; i < 8; ++i) {
        int u = i * 512 + t;
        int r = u >> 6, kg = u & 63;
        const float4* src = (const float4*)(ctx + (size_t)(row0 + r) * DC + kg * 8);
        float4 va = src[0], vb = src[1];
        unsigned int p0 = pk2(va.x, va.y), p1 = pk2(va.z, va.w);
        unsigned int p2 = pk2(vb.x, vb.y), p3 = pk2(vb.z, vb.w);
        uint4 pk = {p0, p1, p2, p3};
        *(uint4*)((char*)ctxs + ((r * 1024 + kg * 16) ^ ((r & 7) << 4))) = pk;
    }
    __syncthreads();

    // ---- K-loop: free-running, no barriers ----
    f32x4 acc[4][4] = {};
    #pragma unroll 2
    for (int s = 0; s < 16; ++s) {
        bf16x8 bfr[4];
        const us8* wsrc = (const us8*)(WtF +
            (((size_t)s * 32 + w * 4) * 64 + lane) * 8);
        #pragma unroll
        for (int fn = 0; fn < 4; ++fn)
            bfr[fn] = *(const bf16x8*)(wsrc + fn * 64);
        bf16x8 af[4];
        #pragma unroll
        for (int fm = 0; fm < 4; ++fm) {
            int r = fm * 16 + lr;
            af[fm] = *(const bf16x8*)((const char*)ctxs +
                        ((r * 1024 + s * 64 + half * 16) ^ ((r & 7) << 4)));
        }
        #pragma unroll
        for (int fm = 0; fm < 4; ++fm)
            #pragma unroll
            for (int fn = 0; fn < 4; ++fn)
                acc[fm][fn] = __builtin_amdgcn_mfma_f32_16x16x32_bf16(
                    af[fm], bfr[fn], acc[fm][fn], 0, 0, 0);
    }

    // ---- epilogue: fold tanh, reduce rows ----
    float wv[4], qv[4];
    #pragma unroll
    for (int fn = 0; fn < 4; ++fn) {
        int j = w * 64 + fn * 16 + lr;
        wv[fn] = wsc[j];
        qv[fn] = qb[bidx * DC + j];
    }
    #pragma unroll
    for (int fm = 0; fm < 4; ++fm) {
        #pragma unroll
        for (int reg = 0; reg < 4; ++reg) {
            float ssum = 0.f;
            #pragma unroll
            for (int fn = 0; fn < 4; ++fn)
                ssum += wv[fn] * fast_tanh(qv[fn] + acc[fm][fn][reg]);
            #pragma unroll
            for (int m = 8; m >= 1; m >>= 1)
                ssum += __shfl_xor(ssum, m, 64);
            if (lr == 0)
                sred[w][fm * 16 + half * 4 + reg] = ssum;
        }
    }
    __syncthreads();

    if (t < 64) {                        // wave 0: block softmax partials
        float sc = sred[0][t] + sred[1][t] + sred[2][t] + sred[3][t]
                 + sred[4][t] + sred[5][t] + sred[6][t] + sred[7][t];
        if (mask[row0 + t] != 0) sc = -1e30f;
        scores_ws[row0 + t] = sc;
        float mx = sc;
        #pragma unroll
        for (int m = 32; m >= 1; m >>= 1) mx = fmaxf(mx, __shfl_xor(mx, m, 64));
        float pe = __expf(sc - mx);
        sp[t] = pe;
        float ls = pe;
        #pragma unroll
        for (int m = 32; m >= 1; m >>= 1) ls += __shfl_xor(ls, m, 64);
        if (t == 0) {
            ml_ws[blockIdx.x * 2]     = mx;
            ml_ws[blockIdx.x * 2 + 1] = ls;
        }
    }
    __syncthreads();

    // ---- pv partial: col t, all from LDS ----
    float a0 = 0.f;
    #pragma unroll 8
    for (int s = 0; s < 64; ++s) {
        unsigned int u = *(const unsigned short*)
            ((const char*)ctxs + ((s * 1024 + t * 2) ^ ((s & 7) << 4)));
        a0 += sp[s] * bf2f(u);
    }
    pv_ws[(size_t)blockIdx.x * 512 + t] = a0;
}

// Exact cross-block softmax merge: attn + ctxv
__global__ __launch_bounds__(256) void combine_kernel(
    const float* __restrict__ pv, const float* __restrict__ ml,
    const float* __restrict__ scores,
    float* __restrict__ ctxv, float* __restrict__ attn)
{
    int b = blockIdx.x, t = threadIdx.x;
    __shared__ float sm[32], sl[32], sw[32];
    if (t < 32) {
        sm[t] = ml[(b * 32 + t) * 2];
        sl[t] = ml[(b * 32 + t) * 2 + 1];
    }
    __syncthreads();
    float mstar = -1e30f;
    #pragma unroll
    for (int i = 0; i < 32; ++i) mstar = fmaxf(mstar, sm[i]);
    if (t < 32) sw[t] = __expf(sm[t] - mstar);
    __syncthreads();
    float L = 0.f;
    #pragma unroll
    for (int i = 0; i < 32; ++i) L += sw[i] * sl[i];
    float invL = 1.f / L;

    int d0 = t * 2;
    float c0 = 0.f, c1 = 0.f;
    #pragma unroll
    for (int i = 0; i < 32; ++i) {
        float w = sw[i];
        const float2 v = *(const float2*)(pv + (size_t)(b * 32 + i) * 512 + d0);
        c0 += w * v.x; c1 += w * v.y;
    }
    ctxv[b * DC + d0]     = c0 * invL;
    ctxv[b * DC + d0 + 1] = c1 * invL;

    for (int s = t; s < S_; s += 256)
        attn[(size_t)b * S_ + s] = __expf(scores[(size_t)b * S_ + s] - mstar) * invL;
}

// x[b][i] = tanh(cat(ctxv,input) @ W_out + b_out)
__global__ __launch_bounds__(256) void out_kernel(
    const float* __restrict__ ctxv, const float* __restrict__ input,
    const float* __restrict__ W_out, const float* __restrict__ b_out,
    float* __restrict__ x)
{
    __shared__ float sc[DC + DI];
    int b = blockIdx.x, t = threadIdx.x;
    for (int i = t; i < DC; i += 256) sc[i] = ctxv[b * DC + i];
    for (int i = t; i < DI; i += 256) sc[DC + i] = input[b * DI + i];
    __syncthreads();
    int e0 = t * 2;
    float a0 = b_out[e0], a1 = b_out[e0 + 1];
    for (int d = 0; d < DC + DI; ++d) {
        float v = sc[d];
        const float* w = W_out + (size_t)d * DI + e0;
        a0 += v * w[0];
        a1 += v * w[1];
    }
    x[b * DI + e0] = fast_tanh(a0);
    x[b * DI + e0 + 1] = fast_tanh(a1);
}

extern "C" void kernel_launch(void* const* d_in, const int* in_sizes, int n_in,
                              void* d_out, int out_size, void* d_ws, size_t ws_size,
                              hipStream_t stream) {
    const float* input = (const float*)d_in[0];
    const float* ctx   = (const float*)d_in[1];
    const int*   mask  = (const int*)d_in[2];
    const float* W_in  = (const float*)d_in[3];
    const float* b_in  = (const float*)d_in[4];
    const float* W_ctx = (const float*)d_in[5];
    const float* b_ctx = (const float*)d_in[6];
    const float* wsc   = (const float*)d_in[7];
    const float* W_out = (const float*)d_in[8];
    const float* b_out = (const float*)d_in[9];

    float* x_out = (float*)d_out;               // [B, DI]
    float* attn  = (float*)d_out + B_ * DI;     // [B, S]

    const int NBLK = (B_ * S_) / 64;            // 4096 score blocks

    char* ws = (char*)d_ws;
    float* qb = (float*)ws;                    ws += (size_t)B_ * DC * 4;
    unsigned short* WtF = (unsigned short*)ws; ws += (size_t)DC * DC * 2;
    float* scores_ws = (float*)ws;             ws += (size_t)B_ * S_ * 4;
    float* pv_ws = (float*)ws;                 ws += (size_t)NBLK * 512 * 4;
    float* ml_ws = (float*)ws;                 ws += (size_t)NBLK * 2 * 4;
    float* ctxv = (float*)ws;                  ws += (size_t)B_ * DC * 4;

    qb_kernel<<<B_, 256, 0, stream>>>(input, W_in, b_in, b_ctx, qb);
    wt_kernel<<<(16 * 32 * 64) / 256, 256, 0, stream>>>(W_ctx, WtF);
    score_kernel<<<NBLK, 512, 0, stream>>>(ctx, WtF, qb, wsc, mask,
                                           scores_ws, pv_ws, ml_ws);
    combine_kernel<<<B_, 256, 0, stream>>>(pv_ws, ml_ws, scores_ws, ctxv, attn);
    out_kernel<<<B_, 256, 0, stream>>>(ctxv, input, W_out, b_out, x_out);
}